// Round 6
// baseline (95.520 us; speedup 1.0000x reference)
//
#include <hip/hip_runtime.h>

// N=4096 rows, D=128 in-dim, P=128 pe-dim, H=256 hidden.
// out: (N, 129) fp32, col 0 = ones, col j+1 = x[:,j] * (1 + g_j)
//
//   base[n][h] = sum_i x[n][i]*W1[i][h] + b1[h]     (kernel 1, split-K -> 2 ws slabs)
//   g = sum_h relu(base[n][h] + W1[128+j][h] - x[n][j]*W1[j][h]) * W2[h] + b2
//   out[n][1+j] = x[n][j] * (1 + g)

#define NROWS 4096
#define DIN   128
#define HDIM  256
#define JCH   8

typedef float sfloat16 __attribute__((ext_vector_type(16)));

// ---------------- Kernel 1: split-K partial GEMM ----------------
// grid (128, 4, 2) = 1024 blocks (4/CU -> 4 waves/SIMD), 256 threads.
// Block: 32 rows x 64 h x 64 k. x k-half staged transposed in LDS (stride 36).
// split 0 adds b1; main combines the two partial slabs.
__global__ __launch_bounds__(256) void nimo_base(
    const float* __restrict__ x, const float* __restrict__ W1,
    const float* __restrict__ b1, float* __restrict__ baseb)
{
    __shared__ float xs[64 * 36];
    const int tid  = threadIdx.x;
    const int row0 = blockIdx.x * 32;
    const int h0   = blockIdx.y * 64;
    const int k0   = blockIdx.z * 64;
    float* __restrict__ pbuf = baseb + (size_t)blockIdx.z * (NROWS * HDIM);

    {   // stage x[row0..row0+31][k0..k0+63] transposed: 8 floats/thread
        const int bidx = tid * 8;
        const int r = bidx >> 6;             // 0..31
        const int c = bidx & 63;             // 0..56 step 8
        #pragma unroll
        for (int u = 0; u < 2; ++u) {
            const float4 v = *(const float4*)(x + (size_t)(row0 + r) * DIN + k0 + c + u * 4);
            xs[(c + u * 4 + 0) * 36 + r] = v.x;
            xs[(c + u * 4 + 1) * 36 + r] = v.y;
            xs[(c + u * 4 + 2) * 36 + r] = v.z;
            xs[(c + u * 4 + 3) * 36 + r] = v.w;
        }
    }
    __syncthreads();

    const int tx = tid & 31;                 // h pair
    const int ty = tid >> 5;                 // row quad
    const float* __restrict__ wcol = W1 + (size_t)k0 * HDIM + h0 + tx * 2;

    float2 acc[4];
    #pragma unroll
    for (int u = 0; u < 4; ++u) { acc[u].x = 0.f; acc[u].y = 0.f; }

    #pragma unroll 8
    for (int k = 0; k < 64; ++k) {
        const float2 w  = *(const float2*)(wcol + (size_t)k * HDIM);
        const float4 xv = *(const float4*)(&xs[k * 36 + ty * 4]);
        acc[0].x = fmaf(xv.x, w.x, acc[0].x); acc[0].y = fmaf(xv.x, w.y, acc[0].y);
        acc[1].x = fmaf(xv.y, w.x, acc[1].x); acc[1].y = fmaf(xv.y, w.y, acc[1].y);
        acc[2].x = fmaf(xv.z, w.x, acc[2].x); acc[2].y = fmaf(xv.z, w.y, acc[2].y);
        acc[3].x = fmaf(xv.w, w.x, acc[3].x); acc[3].y = fmaf(xv.w, w.y, acc[3].y);
    }

    float2 bv = make_float2(0.f, 0.f);
    if (blockIdx.z == 0) bv = *(const float2*)(b1 + h0 + tx * 2);
    #pragma unroll
    for (int u = 0; u < 4; ++u) {
        float2 o; o.x = acc[u].x + bv.x; o.y = acc[u].y + bv.y;
        *(float2*)(pbuf + (size_t)(row0 + ty * 4 + u) * HDIM + h0 + tx * 2) = o;
    }
}

// ---------------- Kernel 2: masked-MLP evaluation ----------------
// grid (64, 16), block 1024 = 16 waves. Wave q owns h-chunk [q*16, q*16+16);
// lane = row (r = tid&63). Register-resident bb[16] (p0+p1 combined), w2r[16]
// (constant-index access only -> no scratch). W1 rows wave-uniform in SGPRs:
// ONE asm block per 2 jj issues 4x s_load_dwordx16 + single lgkmcnt(0)
// (SMEM may return OOO -> lgkmcnt(0) only; batching halves stall rounds).
// 16-way h-partials combined once via LDS. LDS ~36 KB.
__global__ __launch_bounds__(1024, 8) void nimo_main(
    const float* __restrict__ x, const float* __restrict__ W1,
    const float* __restrict__ W2, const float* __restrict__ b2,
    const float* __restrict__ baseb, float* __restrict__ out)
{
    __shared__ float xs[64][JCH + 1];
    __shared__ float part[16][JCH][66];

    const int tid  = threadIdx.x;
    const int r    = tid & 63;
    const int q    = tid >> 6;             // wave id 0..15
    const int row0 = blockIdx.x * 64;
    const int row  = row0 + r;
    const int j0   = blockIdx.y * JCH;
    const int h0   = q * 16;

    if (tid < 512) {
        const int xr = tid >> 3;
        const int xc = tid & 7;
        xs[xr][xc] = x[(size_t)(row0 + xr) * DIN + j0 + xc];
    }

    // bb = p0 + p1 (split-K combine), w2r; constant-index writes -> VGPRs
    float bb[16], w2r[16];
    {
        const float4* a0  = (const float4*)(baseb + (size_t)row * HDIM + h0);
        const float4* a1  = (const float4*)(baseb + (size_t)NROWS * HDIM + (size_t)row * HDIM + h0);
        const float4* wp2 = (const float4*)(W2 + h0);
        #pragma unroll
        for (int u = 0; u < 4; ++u) {
            const float4 v0 = a0[u];
            const float4 v1 = a1[u];
            bb[u * 4 + 0] = v0.x + v1.x; bb[u * 4 + 1] = v0.y + v1.y;
            bb[u * 4 + 2] = v0.z + v1.z; bb[u * 4 + 3] = v0.w + v1.w;
            const float4 w = wp2[u];
            w2r[u * 4 + 0] = w.x; w2r[u * 4 + 1] = w.y;
            w2r[u * 4 + 2] = w.z; w2r[u * 4 + 3] = w.w;
        }
    }
    __syncthreads();

    #pragma unroll
    for (int jp = 0; jp < JCH; jp += 2) {
        unsigned off = (unsigned)(((j0 + jp) * HDIM + h0) * 4);
        off = __builtin_amdgcn_readfirstlane(off);
        sfloat16 wa0, wp0, wa1, wp1;
        asm volatile(
            "s_load_dwordx16 %0, %4, 0x0\n\t"
            "s_load_dwordx16 %1, %4, 0x20000\n\t"   // +128*256*4 -> W1[128+j]
            "s_load_dwordx16 %2, %4, 0x400\n\t"     // +256*4     -> W1[j+1]
            "s_load_dwordx16 %3, %4, 0x20400\n\t"
            "s_waitcnt lgkmcnt(0)"
            : "=s"(wa0), "=s"(wp0), "=s"(wa1), "=s"(wp1)
            : "s"((unsigned long long)(uintptr_t)W1 + off));

        const float xj0 = xs[r][jp];
        const float xj1 = xs[r][jp + 1];
        float acc0 = 0.f, acc1 = 0.f;
        #pragma unroll
        for (int h = 0; h < 16; ++h) {
            float t0 = bb[h] + wp0[h];
            t0 = fmaf(-xj0, wa0[h], t0);
            t0 = fmaxf(t0, 0.f);
            acc0 = fmaf(t0, w2r[h], acc0);
            float t1 = bb[h] + wp1[h];
            t1 = fmaf(-xj1, wa1[h], t1);
            t1 = fmaxf(t1, 0.f);
            acc1 = fmaf(t1, w2r[h], acc1);
        }
        part[q][jp][r]     = acc0;
        part[q][jp + 1][r] = acc1;
    }
    __syncthreads();

    const float b2s = b2[0];
    if (blockIdx.y == 0 && tid < 64) out[(size_t)(row0 + tid) * 129] = 1.0f;

    if (tid < 512) {
        const int rr = tid >> 3;              // 0..63
        const int jj = tid & 7;               // 0..7
        float g = 0.f;
        #pragma unroll
        for (int qq = 0; qq < 16; ++qq) g += part[qq][jj][rr];
        const float xv = xs[rr][jj];
        out[(size_t)(row0 + rr) * 129 + 1 + j0 + jj] = xv * (1.0f + g + b2s);
    }
}

extern "C" void kernel_launch(void* const* d_in, const int* in_sizes, int n_in,
                              void* d_out, int out_size, void* d_ws, size_t ws_size,
                              hipStream_t stream) {
    const float* x  = (const float*)d_in[0];   // 4096*128
    const float* W1 = (const float*)d_in[1];   // 256*256
    const float* b1 = (const float*)d_in[2];   // 256
    const float* W2 = (const float*)d_in[3];   // 256
    const float* b2 = (const float*)d_in[4];   // 1
    float* out = (float*)d_out;                // 4096*129
    float* baseb = (float*)d_ws;               // 2 x 4 MB partial slabs

    nimo_base<<<dim3(NROWS / 32, HDIM / 64, 2), 256, 0, stream>>>(x, W1, b1, baseb);
    nimo_main<<<dim3(NROWS / 64, DIN / JCH), 1024, 0, stream>>>(x, W1, W2, b2, baseb, out);
}

// Round 7
// 88.889 us; speedup vs baseline: 1.0746x; 1.0746x over previous
//
#include <hip/hip_runtime.h>

// N=4096 rows, D=128 in-dim, P=128 pe-dim, H=256 hidden.
// out: (N, 129) fp32, col 0 = ones, col j+1 = x[:,j] * (1 + g_j)
//
//   base[n][h] = sum_i x[n][i]*W1[i][h] + b1[h]          (kernel 1 -> d_ws)
//   g = sum_h relu(base[n][h] + W1[128+j][h] - x[n][j]*W1[j][h]) * W2[h] + b2
//   out[n][1+j] = x[n][j] * (1 + g)

#define NROWS 4096
#define DIN   128
#define HDIM  256
#define JCH   8

typedef float sfloat16 __attribute__((ext_vector_type(16)));

// ---------------- Kernel 1: base = x @ W1[:128] + b1 ----------------
// (r5 form, unchanged — isolate this round's experiment to nimo_main)
__global__ __launch_bounds__(256) void nimo_base(
    const float* __restrict__ x, const float* __restrict__ W1,
    const float* __restrict__ b1, float* __restrict__ baseb)
{
    __shared__ float xs[DIN * 36];
    const int tid  = threadIdx.x;
    const int row0 = blockIdx.x * 32;
    const int h0   = blockIdx.y * 64;

    {
        const int bidx = tid * 16;
        const int r = bidx >> 7;
        const int c = bidx & 127;
        #pragma unroll
        for (int u = 0; u < 4; ++u) {
            const float4 v = *(const float4*)(x + (size_t)(row0 + r) * DIN + c + u * 4);
            xs[(c + u * 4 + 0) * 36 + r] = v.x;
            xs[(c + u * 4 + 1) * 36 + r] = v.y;
            xs[(c + u * 4 + 2) * 36 + r] = v.z;
            xs[(c + u * 4 + 3) * 36 + r] = v.w;
        }
    }
    __syncthreads();

    const int tx = tid & 31;
    const int ty = tid >> 5;
    const float* __restrict__ wcol = W1 + h0 + tx * 2;

    float2 acc[4];
    #pragma unroll
    for (int u = 0; u < 4; ++u) { acc[u].x = 0.f; acc[u].y = 0.f; }

    #pragma unroll 8
    for (int k = 0; k < DIN; ++k) {
        const float2 w  = *(const float2*)(wcol + (size_t)k * HDIM);
        const float4 xv = *(const float4*)(&xs[k * 36 + ty * 4]);
        acc[0].x = fmaf(xv.x, w.x, acc[0].x); acc[0].y = fmaf(xv.x, w.y, acc[0].y);
        acc[1].x = fmaf(xv.y, w.x, acc[1].x); acc[1].y = fmaf(xv.y, w.y, acc[1].y);
        acc[2].x = fmaf(xv.z, w.x, acc[2].x); acc[2].y = fmaf(xv.z, w.y, acc[2].y);
        acc[3].x = fmaf(xv.w, w.x, acc[3].x); acc[3].y = fmaf(xv.w, w.y, acc[3].y);
    }

    const float2 bv = *(const float2*)(b1 + h0 + tx * 2);
    #pragma unroll
    for (int u = 0; u < 4; ++u) {
        float2 o; o.x = acc[u].x + bv.x; o.y = acc[u].y + bv.y;
        *(float2*)(baseb + (size_t)(row0 + ty * 4 + u) * HDIM + h0 + tx * 2) = o;
    }
}

// ---------------- Kernel 2: masked-MLP evaluation ----------------
// grid (64, 16), block 1024 = 16 waves; wave q owns h-chunk [q*16, q*16+16);
// lane = row. Register-resident bb[16], w2r[16] (constant-index only).
// W1 rows wave-uniform in SGPRs via s_load_dwordx16, SOFTWARE-PIPELINED:
// issue round k+1's loads before consuming round k; the wait is tied to the
// consumed buffer via "+s" so steady-state SMEM latency hides behind the
// 128 VALU insts of the previous round. One uniform base address; per-round
// offsets are compile-time immediates (jj*0x400; +0x20000 for the pe half).
__global__ __launch_bounds__(1024, 8) void nimo_main(
    const float* __restrict__ x, const float* __restrict__ W1,
    const float* __restrict__ W2, const float* __restrict__ b2,
    const float* __restrict__ baseb, float* __restrict__ out)
{
    __shared__ float xs[64][JCH + 1];
    __shared__ float part[16][JCH][66];

    const int tid  = threadIdx.x;
    const int r    = tid & 63;
    const int q    = tid >> 6;             // wave id 0..15
    const int row0 = blockIdx.x * 64;
    const int row  = row0 + r;
    const int j0   = blockIdx.y * JCH;
    const int h0   = q * 16;

    // wave-uniform W1 base address (j0 row, this wave's h-chunk)
    unsigned off0 = (unsigned)((j0 * HDIM + h0) * 4);
    off0 = __builtin_amdgcn_readfirstlane(off0);
    const unsigned long long wbase = (unsigned long long)(uintptr_t)W1 + off0;

    sfloat16 waA, wpA, waB, wpB;
    // preload round 0 (overlaps with staging + bb/w2r global loads)
    asm volatile(
        "s_load_dwordx16 %0, %2, 0x0\n\t"
        "s_load_dwordx16 %1, %2, 0x20000"
        : "=s"(waA), "=s"(wpA) : "s"(wbase));

    if (tid < 512) {
        const int xr = tid >> 3;
        const int xc = tid & 7;
        xs[xr][xc] = x[(size_t)(row0 + xr) * DIN + j0 + xc];
    }

    float bb[16], w2r[16];
    {
        const float4* bp  = (const float4*)(baseb + (size_t)row * HDIM + h0);
        const float4* wp2 = (const float4*)(W2 + h0);
        #pragma unroll
        for (int u = 0; u < 4; ++u) {
            const float4 v = bp[u];
            bb[u * 4 + 0] = v.x; bb[u * 4 + 1] = v.y;
            bb[u * 4 + 2] = v.z; bb[u * 4 + 3] = v.w;
            const float4 w = wp2[u];
            w2r[u * 4 + 0] = w.x; w2r[u * 4 + 1] = w.y;
            w2r[u * 4 + 2] = w.z; w2r[u * 4 + 3] = w.w;
        }
    }
    __syncthreads();

    #pragma unroll
    for (int jp = 0; jp < JCH; jp += 2) {
        // ---- even round: wait A, prefetch B(jp+1), consume A ----
        asm volatile("s_waitcnt lgkmcnt(0)" : "+s"(waA), "+s"(wpA));
        asm volatile(
            "s_load_dwordx16 %0, %2, %3\n\t"
            "s_load_dwordx16 %1, %2, %4"
            : "=s"(waB), "=s"(wpB)
            : "s"(wbase), "i"((jp + 1) * 0x400), "i"(0x20000 + (jp + 1) * 0x400));
        {
            const float xj = xs[r][jp];
            float acc = 0.f;
            #pragma unroll
            for (int h = 0; h < 16; ++h) {
                float t = bb[h] + wpA[h];
                t = fmaf(-xj, waA[h], t);
                t = fmaxf(t, 0.f);
                acc = fmaf(t, w2r[h], acc);
            }
            part[q][jp][r] = acc;
        }
        // ---- odd round: wait B, prefetch A(jp+2), consume B ----
        asm volatile("s_waitcnt lgkmcnt(0)" : "+s"(waB), "+s"(wpB));
        if (jp + 2 < JCH) {
            asm volatile(
                "s_load_dwordx16 %0, %2, %3\n\t"
                "s_load_dwordx16 %1, %2, %4"
                : "=s"(waA), "=s"(wpA)
                : "s"(wbase), "i"((jp + 2) * 0x400), "i"(0x20000 + (jp + 2) * 0x400));
        }
        {
            const float xj = xs[r][jp + 1];
            float acc = 0.f;
            #pragma unroll
            for (int h = 0; h < 16; ++h) {
                float t = bb[h] + wpB[h];
                t = fmaf(-xj, waB[h], t);
                t = fmaxf(t, 0.f);
                acc = fmaf(t, w2r[h], acc);
            }
            part[q][jp + 1][r] = acc;
        }
    }
    __syncthreads();

    const float b2s = b2[0];
    if (blockIdx.y == 0 && tid < 64) out[(size_t)(row0 + tid) * 129] = 1.0f;

    if (tid < 512) {
        const int rr = tid >> 3;
        const int jj = tid & 7;
        float g = 0.f;
        #pragma unroll
        for (int qq = 0; qq < 16; ++qq) g += part[qq][jj][rr];
        const float xv = xs[rr][jj];
        out[(size_t)(row0 + rr) * 129 + 1 + j0 + jj] = xv * (1.0f + g + b2s);
    }
}

extern "C" void kernel_launch(void* const* d_in, const int* in_sizes, int n_in,
                              void* d_out, int out_size, void* d_ws, size_t ws_size,
                              hipStream_t stream) {
    const float* x  = (const float*)d_in[0];   // 4096*128
    const float* W1 = (const float*)d_in[1];   // 256*256
    const float* b1 = (const float*)d_in[2];   // 256
    const float* W2 = (const float*)d_in[3];   // 256
    const float* b2 = (const float*)d_in[4];   // 1
    float* out = (float*)d_out;                // 4096*129
    float* baseb = (float*)d_ws;               // 4 MB scratch

    nimo_base<<<dim3(NROWS / 32, HDIM / 64), 256, 0, stream>>>(x, W1, b1, baseb);
    nimo_main<<<dim3(NROWS / 64, DIN / JCH), 1024, 0, stream>>>(x, W1, W2, b2, baseb, out);
}

// Round 8
// 88.041 us; speedup vs baseline: 1.0849x; 1.0096x over previous
//
#include <hip/hip_runtime.h>

// N=4096 rows, D=128 in-dim, P=128 pe-dim, H=256 hidden.
// out: (N, 129) fp32, col 0 = ones, col j+1 = x[:,j] * (1 + g_j)
//
//   base[n][h] = sum_i x[n][i]*W1[i][h] + b1[h]          (kernel 1 -> d_ws)
//   g = sum_h relu(base[n][h] + W1[128+j][h] - x[n][j]*W1[j][h]) * W2[h] + b2
//   out[n][1+j] = x[n][j] * (1 + g)

#define NROWS 4096
#define DIN   128
#define HDIM  256
#define JCH   32   // j's per block (fused: bb loaded once per 32 j, was 8)
#define JG    8    // j's per part-combine group

typedef float sfloat16 __attribute__((ext_vector_type(16)));

// ---------------- Kernel 1: base = x @ W1[:128] + b1 ----------------
// (r5 form, unchanged — ~4 us, not the bottleneck)
__global__ __launch_bounds__(256) void nimo_base(
    const float* __restrict__ x, const float* __restrict__ W1,
    const float* __restrict__ b1, float* __restrict__ baseb)
{
    __shared__ float xs[DIN * 36];
    const int tid  = threadIdx.x;
    const int row0 = blockIdx.x * 32;
    const int h0   = blockIdx.y * 64;

    {
        const int bidx = tid * 16;
        const int r = bidx >> 7;
        const int c = bidx & 127;
        #pragma unroll
        for (int u = 0; u < 4; ++u) {
            const float4 v = *(const float4*)(x + (size_t)(row0 + r) * DIN + c + u * 4);
            xs[(c + u * 4 + 0) * 36 + r] = v.x;
            xs[(c + u * 4 + 1) * 36 + r] = v.y;
            xs[(c + u * 4 + 2) * 36 + r] = v.z;
            xs[(c + u * 4 + 3) * 36 + r] = v.w;
        }
    }
    __syncthreads();

    const int tx = tid & 31;
    const int ty = tid >> 5;
    const float* __restrict__ wcol = W1 + h0 + tx * 2;

    float2 acc[4];
    #pragma unroll
    for (int u = 0; u < 4; ++u) { acc[u].x = 0.f; acc[u].y = 0.f; }

    #pragma unroll 8
    for (int k = 0; k < DIN; ++k) {
        const float2 w  = *(const float2*)(wcol + (size_t)k * HDIM);
        const float4 xv = *(const float4*)(&xs[k * 36 + ty * 4]);
        acc[0].x = fmaf(xv.x, w.x, acc[0].x); acc[0].y = fmaf(xv.x, w.y, acc[0].y);
        acc[1].x = fmaf(xv.y, w.x, acc[1].x); acc[1].y = fmaf(xv.y, w.y, acc[1].y);
        acc[2].x = fmaf(xv.z, w.x, acc[2].x); acc[2].y = fmaf(xv.z, w.y, acc[2].y);
        acc[3].x = fmaf(xv.w, w.x, acc[3].x); acc[3].y = fmaf(xv.w, w.y, acc[3].y);
    }

    const float2 bv = *(const float2*)(b1 + h0 + tx * 2);
    #pragma unroll
    for (int u = 0; u < 4; ++u) {
        float2 o; o.x = acc[u].x + bv.x; o.y = acc[u].y + bv.y;
        *(float2*)(baseb + (size_t)(row0 + ty * 4 + u) * HDIM + h0 + tx * 2) = o;
    }
}

// ---------------- Kernel 2: masked-MLP evaluation (j-fused) ----------------
// grid (64, 4) = 256 blocks (1/CU), block 1024 = 16 waves.
// Wave q owns h-chunk [q*16, q*16+16); lane = row. bb[16], w2r[16] register-
// resident and loaded ONCE per 32 j (was per 8 j: baseb HBM re-read 64->16 MB).
// W1 rows via s_load_dwordx16 (wave-uniform SGPRs), depth-1 dbl-buffered asm.
// xj hoisted to VGPRs per 8-j group so no compiler lgkm-wait lands in the
// pipelined rounds. Partials combined + written every 8 j (part 33.8 KB LDS).
__global__ __launch_bounds__(1024, 4) void nimo_main(
    const float* __restrict__ x, const float* __restrict__ W1,
    const float* __restrict__ W2, const float* __restrict__ b2,
    const float* __restrict__ baseb, float* __restrict__ out)
{
    __shared__ float xs[64][33];           // x tile, stride 33: conflict-free col reads
    __shared__ float part[16][JG][66];     // per-wave h-partials, one 8-j group

    const int tid  = threadIdx.x;
    const int r    = tid & 63;
    const int q    = tid >> 6;             // wave id 0..15
    const int row0 = blockIdx.x * 64;
    const int row  = row0 + r;
    const int j0   = blockIdx.y * JCH;
    const int h0   = q * 16;

    // stage x tile: 64 rows x 32 j, 2 floats/thread, coalesced float2
    {
        const int rr = tid >> 4;           // 0..63
        const int jc = (tid & 15) * 2;     // 0..30
        const float2 v = *(const float2*)(x + (size_t)(row0 + rr) * DIN + j0 + jc);
        xs[rr][jc] = v.x; xs[rr][jc + 1] = v.y;
    }

    // per-lane resident data (constant-index writes -> VGPRs, no scratch)
    float bb[16], w2r[16];
    {
        const float4* bp  = (const float4*)(baseb + (size_t)row * HDIM + h0);
        const float4* wp2 = (const float4*)(W2 + h0);
        #pragma unroll
        for (int u = 0; u < 4; ++u) {
            const float4 v = bp[u];
            bb[u * 4 + 0] = v.x; bb[u * 4 + 1] = v.y;
            bb[u * 4 + 2] = v.z; bb[u * 4 + 3] = v.w;
            const float4 w = wp2[u];
            w2r[u * 4 + 0] = w.x; w2r[u * 4 + 1] = w.y;
            w2r[u * 4 + 2] = w.z; w2r[u * 4 + 3] = w.w;
        }
    }
    const float b2s = b2[0];
    if (blockIdx.y == 0 && tid < 64) out[(size_t)(row0 + tid) * 129] = 1.0f;
    __syncthreads();

    // wave-uniform W1 base for this block's j-range + wave's h-chunk
    unsigned off0 = (unsigned)((j0 * HDIM + h0) * 4);
    off0 = __builtin_amdgcn_readfirstlane(off0);
    const unsigned long long wbase = (unsigned long long)(uintptr_t)W1 + off0;

    for (int g = 0; g < JCH / JG; ++g) {
        const unsigned long long wb = wbase + (unsigned)(g * JG * HDIM * 4);

        sfloat16 waA, wpA, waB, wpB;
        asm volatile(                      // preload round 0 of the group
            "s_load_dwordx16 %0, %2, 0x0\n\t"
            "s_load_dwordx16 %1, %2, 0x20000"
            : "=s"(waA), "=s"(wpA) : "s"(wb));

        // hoist the group's xj values (LDS reads + their waits happen HERE,
        // overlapped with the preload, not inside the pipelined rounds)
        float xv[JG];
        #pragma unroll
        for (int i = 0; i < JG; ++i) xv[i] = xs[r][g * JG + i];

        #pragma unroll
        for (int p = 0; p < JG; p += 2) {
            // even round: wait A, prefetch B(p+1), consume A
            asm volatile("s_waitcnt lgkmcnt(0)" : "+s"(waA), "+s"(wpA));
            asm volatile(
                "s_load_dwordx16 %0, %2, %3\n\t"
                "s_load_dwordx16 %1, %2, %4"
                : "=s"(waB), "=s"(wpB)
                : "s"(wb), "i"((p + 1) * 0x400), "i"(0x20000 + (p + 1) * 0x400));
            {
                const float xj = xv[p];
                float acc = 0.f;
                #pragma unroll
                for (int h = 0; h < 16; ++h) {
                    float t = bb[h] + wpA[h];
                    t = fmaf(-xj, waA[h], t);
                    t = fmaxf(t, 0.f);
                    acc = fmaf(t, w2r[h], acc);
                }
                part[q][p][r] = acc;
            }
            // odd round: wait B, prefetch A(p+2), consume B
            asm volatile("s_waitcnt lgkmcnt(0)" : "+s"(waB), "+s"(wpB));
            if (p + 2 < JG) {
                asm volatile(
                    "s_load_dwordx16 %0, %2, %3\n\t"
                    "s_load_dwordx16 %1, %2, %4"
                    : "=s"(waA), "=s"(wpA)
                    : "s"(wb), "i"((p + 2) * 0x400), "i"(0x20000 + (p + 2) * 0x400));
            }
            {
                const float xj = xv[p + 1];
                float acc = 0.f;
                #pragma unroll
                for (int h = 0; h < 16; ++h) {
                    float t = bb[h] + wpB[h];
                    t = fmaf(-xj, waB[h], t);
                    t = fmaxf(t, 0.f);
                    acc = fmaf(t, w2r[h], acc);
                }
                part[q][p + 1][r] = acc;
            }
        }
        __syncthreads();

        // combine 16 h-partials for this 8-j group; semi-coalesced out writes
        if (tid < 512) {
            const int rr = tid >> 3;       // 0..63
            const int jj = tid & 7;        // 0..7
            float gsum = 0.f;
            #pragma unroll
            for (int qq = 0; qq < 16; ++qq) gsum += part[qq][jj][rr];
            const float xvv = xs[rr][g * JG + jj];
            out[(size_t)(row0 + rr) * 129 + 1 + j0 + g * JG + jj] =
                xvv * (1.0f + gsum + b2s);
        }
        __syncthreads();
    }
}

extern "C" void kernel_launch(void* const* d_in, const int* in_sizes, int n_in,
                              void* d_out, int out_size, void* d_ws, size_t ws_size,
                              hipStream_t stream) {
    const float* x  = (const float*)d_in[0];   // 4096*128
    const float* W1 = (const float*)d_in[1];   // 256*256
    const float* b1 = (const float*)d_in[2];   // 256
    const float* W2 = (const float*)d_in[3];   // 256
    const float* b2 = (const float*)d_in[4];   // 1
    float* out = (float*)d_out;                // 4096*129
    float* baseb = (float*)d_ws;               // 4 MB scratch

    nimo_base<<<dim3(NROWS / 32, HDIM / 64), 256, 0, stream>>>(x, W1, b1, baseb);
    nimo_main<<<dim3(NROWS / 64, DIN / JCH), 1024, 0, stream>>>(x, W1, W2, b2, baseb, out);
}